// Round 1
// baseline (453.509 us; speedup 1.0000x reference)
//
#include <hip/hip_runtime.h>

#define B_DIM 4
#define T_DIM 300
#define U_DIM 80
#define UP1   81
#define V_DIM 1024
#define NINNER 512
#define NROWS (B_DIM * T_DIM * UP1)   /* 97200 */
#define EP_ROWS (B_DIM * T_DIM)       /* 1200 */
#define DP_ROWS (B_DIM * UP1)         /* 324 */

typedef float f32x4 __attribute__((ext_vector_type(4)));
typedef short short8 __attribute__((ext_vector_type(8)));
typedef short short4v __attribute__((ext_vector_type(4)));
typedef __bf16 bf16x8 __attribute__((ext_vector_type(8)));

static __device__ __forceinline__ unsigned short f2bf(float f) {
  unsigned int u = __builtin_bit_cast(unsigned int, f);
  return (unsigned short)((u + 0x7fffu + ((u >> 16) & 1u)) >> 16);
}
static __device__ __forceinline__ float fexp(float x) {
  return __builtin_amdgcn_exp2f(x * 1.44269504088896341f);
}
static __device__ __forceinline__ float flog(float x) {
  return __builtin_amdgcn_logf(x) * 0.693147180559945310f;
}
static __device__ __forceinline__ float tanh_fast(float x) {
  float e = __builtin_amdgcn_exp2f(x * 2.88539008177792681f); // exp(2x)
  return 1.0f - 2.0f * __builtin_amdgcn_rcpf(e + 1.0f);
}

// ---------------- Kernel 0: weights fp32 -> bf16 ----------------
__global__ __launch_bounds__(256) void cvt_kernel(
    const float* __restrict__ Wf, const float* __restrict__ Wp,
    short* __restrict__ WfB, short* __restrict__ WpB) {
  int idx = blockIdx.x * 256 + threadIdx.x;
  const int nf = (512 * 640) / 4;   // 81920
  const int np = (V_DIM * NINNER) / 4;
  if (idx < nf) {
    float4 v = ((const float4*)Wf)[idx];
    short4v o;
    o[0] = (short)f2bf(v.x); o[1] = (short)f2bf(v.y);
    o[2] = (short)f2bf(v.z); o[3] = (short)f2bf(v.w);
    ((short4v*)WfB)[idx] = o;
  } else if (idx < nf + np) {
    int j = idx - nf;
    float4 v = ((const float4*)Wp)[j];
    short4v o;
    o[0] = (short)f2bf(v.x); o[1] = (short)f2bf(v.y);
    o[2] = (short)f2bf(v.z); o[3] = (short)f2bf(v.w);
    ((short4v*)WpB)[j] = o;
  }
}

// ---------------- Kernel 1: enc/dec projections (MFMA bf16) ----------------
// blocks [0,19): ep rows (1200); blocks [19,25): dp rows (324), bf added.
#define EP_BLOCKS 19
__global__ __launch_bounds__(256, 2) void proj_kernel(
    const float* __restrict__ enc, const float* __restrict__ dec,
    const short* __restrict__ WfB, const float* __restrict__ bfv,
    float* __restrict__ ep, float* __restrict__ dp) {
  const bool is_dp = (blockIdx.x >= EP_BLOCKS);
  const int row0 = (is_dp ? (int)blockIdx.x - EP_BLOCKS : (int)blockIdx.x) * 64;
  const int nrows = is_dp ? DP_ROWS : EP_ROWS;
  const float* __restrict__ src = is_dp ? dec : enc;
  const short* __restrict__ wb = WfB + (is_dp ? 320 : 0); // row stride 640
  float* __restrict__ out = is_dp ? dp : ep;

  __shared__ short As[64 * 320];  // 40 KB, XOR-swizzled
  const int tid = threadIdx.x;

  // stage 64 rows x 320 as bf16 (swizzled)
  #pragma unroll
  for (int it = 0; it < 10; ++it) {
    int chunk = it * 256 + tid;        // 2560 chunks of 8 elems
    int m = chunk / 40;
    int c = chunk - m * 40;
    int r = row0 + m;
    short8 hv;
    #pragma unroll
    for (int j = 0; j < 8; ++j) hv[j] = 0;
    if (r < nrows) {
      const float* p = src + (size_t)r * 320 + c * 8;
      float4 a0 = *(const float4*)p;
      float4 a1 = *(const float4*)(p + 4);
      hv[0] = (short)f2bf(a0.x); hv[1] = (short)f2bf(a0.y);
      hv[2] = (short)f2bf(a0.z); hv[3] = (short)f2bf(a0.w);
      hv[4] = (short)f2bf(a1.x); hv[5] = (short)f2bf(a1.y);
      hv[6] = (short)f2bf(a1.z); hv[7] = (short)f2bf(a1.w);
    }
    int off = (m * 640 + c * 16) ^ ((m & 7) << 4);
    *(short8*)((char*)As + off) = hv;
  }
  __syncthreads();

  const int lane = tid & 63, wid = tid >> 6;
  const int lr = lane & 15, g = lane >> 4;

  int lin[4], xm[4];
  #pragma unroll
  for (int mf = 0; mf < 4; ++mf) {
    int row = mf * 16 + lr;
    lin[mf] = row * 640 + g * 16;
    xm[mf] = (row & 7) << 4;
  }

  #pragma unroll
  for (int sc = 0; sc < 2; ++sc) {
    const int n0 = wid * 128 + sc * 64;
    const short* wpc[4];
    float bfc[4];
    #pragma unroll
    for (int nf2 = 0; nf2 < 4; ++nf2) {
      int col = n0 + nf2 * 16 + lr;
      wpc[nf2] = wb + (size_t)col * 640 + g * 8;
      bfc[nf2] = is_dp ? bfv[col] : 0.f;
    }
    f32x4 acc[4][4];
    #pragma unroll
    for (int mf = 0; mf < 4; ++mf)
      #pragma unroll
      for (int nf2 = 0; nf2 < 4; ++nf2)
        acc[mf][nf2] = (f32x4){0.f, 0.f, 0.f, 0.f};

    #pragma unroll 2
    for (int kk = 0; kk < 10; ++kk) {
      bf16x8 av[4], bv[4];
      #pragma unroll
      for (int mf = 0; mf < 4; ++mf) {
        int off = (lin[mf] + (kk << 6)) ^ xm[mf];
        av[mf] = __builtin_bit_cast(bf16x8, *(const short8*)((const char*)As + off));
      }
      #pragma unroll
      for (int nf2 = 0; nf2 < 4; ++nf2)
        bv[nf2] = __builtin_bit_cast(bf16x8, *(const short8*)(wpc[nf2] + kk * 32));
      #pragma unroll
      for (int mf = 0; mf < 4; ++mf)
        #pragma unroll
        for (int nf2 = 0; nf2 < 4; ++nf2)
          acc[mf][nf2] = __builtin_amdgcn_mfma_f32_16x16x32_bf16(av[mf], bv[nf2], acc[mf][nf2], 0, 0, 0);
    }
    #pragma unroll
    for (int mf = 0; mf < 4; ++mf)
      #pragma unroll
      for (int nf2 = 0; nf2 < 4; ++nf2)
        #pragma unroll
        for (int rr = 0; rr < 4; ++rr) {
          int rowl = mf * 16 + g * 4 + rr;
          int grow = row0 + rowl;
          if (grow < nrows) {
            int col = n0 + nf2 * 16 + lr;
            out[(size_t)grow * NINNER + col] = acc[mf][nf2][rr] + bfc[nf2];
          }
        }
  }
}

// ---------------- Kernel 2: fused joint + log-softmax slices ----------------
// Block: 64 rows (b,t,u) x full V=1024. 4 waves, each 256 cols in 4x 64-col
// subchunks. h = tanh(ep+dp) in swizzled LDS; online per-row (max, sumexp).
__global__ __launch_bounds__(256, 2) void joint_kernel(
    const float* __restrict__ ep, const float* __restrict__ dp,
    const short* __restrict__ WpB, const float* __restrict__ bp,
    const int* __restrict__ tgt,
    float* __restrict__ lpb, float* __restrict__ lpe) {
  extern __shared__ char hbuf[];  // 64 * 512 * 2 = 65536 B
  __shared__ int ep_off[64], dp_off[64], bl_off[64], em_off[64], tgt_s[64];
  __shared__ float l0_s[64], lt_s[64];
  __shared__ float wm_s[4][64], ws_s[4][64];

  const int tid = threadIdx.x;
  const int row0 = blockIdx.x * 64;

  if (tid < 64) {
    int gr = row0 + tid;
    if (gr < NROWS) {
      int b = gr / (T_DIM * UP1);
      int rem = gr - b * (T_DIM * UP1);
      int t = rem / UP1;
      int u = rem - t * UP1;
      ep_off[tid] = (b * T_DIM + t) * NINNER;
      dp_off[tid] = (b * UP1 + u) * NINNER;
      bl_off[tid] = (b * T_DIM + t) * UP1 + u;
      em_off[tid] = (u < U_DIM) ? ((b * T_DIM + t) * U_DIM + u) : -1;
      tgt_s[tid] = (u < U_DIM) ? tgt[b * U_DIM + u] : 0;
    } else {
      ep_off[tid] = 0; dp_off[tid] = 0; bl_off[tid] = -1; em_off[tid] = -1; tgt_s[tid] = 0;
    }
    l0_s[tid] = 0.f; lt_s[tid] = 0.f;
  }
  __syncthreads();

  // Phase A: h into LDS (bf16, swizzled)
  #pragma unroll 2
  for (int it = 0; it < 16; ++it) {
    int chunk = it * 256 + tid;    // 4096 chunks of 8
    int m = chunk >> 6, c = chunk & 63;
    short8 hv;
    #pragma unroll
    for (int j = 0; j < 8; ++j) hv[j] = 0;
    if (bl_off[m] >= 0) {
      const float* pe = ep + ep_off[m] + c * 8;
      const float* pd = dp + dp_off[m] + c * 8;
      float4 e0 = *(const float4*)pe;
      float4 e1 = *(const float4*)(pe + 4);
      float4 d0 = *(const float4*)pd;
      float4 d1 = *(const float4*)(pd + 4);
      hv[0] = (short)f2bf(tanh_fast(e0.x + d0.x));
      hv[1] = (short)f2bf(tanh_fast(e0.y + d0.y));
      hv[2] = (short)f2bf(tanh_fast(e0.z + d0.z));
      hv[3] = (short)f2bf(tanh_fast(e0.w + d0.w));
      hv[4] = (short)f2bf(tanh_fast(e1.x + d1.x));
      hv[5] = (short)f2bf(tanh_fast(e1.y + d1.y));
      hv[6] = (short)f2bf(tanh_fast(e1.z + d1.z));
      hv[7] = (short)f2bf(tanh_fast(e1.w + d1.w));
    }
    int off = ((m << 10) + (c << 4)) ^ ((m & 7) << 4);
    *(short8*)(hbuf + off) = hv;
  }
  __syncthreads();

  const int lane = tid & 63, wid = tid >> 6;
  const int lr = lane & 15, g = lane >> 4;

  int lin[4], xm[4];
  #pragma unroll
  for (int mf = 0; mf < 4; ++mf) {
    int row = mf * 16 + lr;
    lin[mf] = (row << 10) + (g << 4);
    xm[mf] = (row & 7) << 4;
  }
  int tv[4][4];
  #pragma unroll
  for (int mf = 0; mf < 4; ++mf)
    #pragma unroll
    for (int rr = 0; rr < 4; ++rr)
      tv[mf][rr] = tgt_s[mf * 16 + g * 4 + rr];

  float runm[4][4], runs[4][4];
  #pragma unroll
  for (int mf = 0; mf < 4; ++mf)
    #pragma unroll
    for (int rr = 0; rr < 4; ++rr) { runm[mf][rr] = -1e30f; runs[mf][rr] = 0.f; }

  for (int sc = 0; sc < 4; ++sc) {
    const int n0 = wid * 256 + sc * 64;
    const short* wpc[4];
    float bpv[4];
    #pragma unroll
    for (int nf = 0; nf < 4; ++nf) {
      int col = n0 + nf * 16 + lr;
      wpc[nf] = WpB + (size_t)col * NINNER + g * 8;
      bpv[nf] = bp[col];
    }
    f32x4 acc[4][4];
    #pragma unroll
    for (int mf = 0; mf < 4; ++mf)
      #pragma unroll
      for (int nf = 0; nf < 4; ++nf)
        acc[mf][nf] = (f32x4){0.f, 0.f, 0.f, 0.f};

    #pragma unroll 2
    for (int kk = 0; kk < 16; ++kk) {
      bf16x8 av[4], bv[4];
      #pragma unroll
      for (int mf = 0; mf < 4; ++mf) {
        int off = (lin[mf] + (kk << 6)) ^ xm[mf];
        av[mf] = __builtin_bit_cast(bf16x8, *(const short8*)(hbuf + off));
      }
      #pragma unroll
      for (int nf = 0; nf < 4; ++nf)
        bv[nf] = __builtin_bit_cast(bf16x8, *(const short8*)(wpc[nf] + kk * 32));
      #pragma unroll
      for (int mf = 0; mf < 4; ++mf)
        #pragma unroll
        for (int nf = 0; nf < 4; ++nf)
          acc[mf][nf] = __builtin_amdgcn_mfma_f32_16x16x32_bf16(av[mf], bv[nf], acc[mf][nf], 0, 0, 0);
    }
    // fold: lane-local running (max, sumexp) over this 64-col subchunk
    #pragma unroll
    for (int mf = 0; mf < 4; ++mf)
      #pragma unroll
      for (int rr = 0; rr < 4; ++rr) {
        float x0 = acc[mf][0][rr] + bpv[0];
        float x1 = acc[mf][1][rr] + bpv[1];
        float x2 = acc[mf][2][rr] + bpv[2];
        float x3 = acc[mf][3][rr] + bpv[3];
        int rowl = mf * 16 + g * 4 + rr;
        if (wid == 0 && sc == 0 && lr == 0) l0_s[rowl] = x0;  // v = 0
        int dtv = tv[mf][rr] - n0;
        if (dtv >= 0 && dtv < 64 && (dtv & 15) == lr) {
          int nfi = dtv >> 4;
          lt_s[rowl] = (nfi == 0) ? x0 : (nfi == 1) ? x1 : (nfi == 2) ? x2 : x3;
        }
        float mx = fmaxf(fmaxf(x0, x1), fmaxf(x2, x3));
        float nm = fmaxf(runm[mf][rr], mx);
        float se = fexp(x0 - nm) + fexp(x1 - nm) + fexp(x2 - nm) + fexp(x3 - nm);
        runs[mf][rr] = runs[mf][rr] * fexp(runm[mf][rr] - nm) + se;
        runm[mf][rr] = nm;
      }
  }
  // combine across the 16 lanes of each group (butterfly)
  #pragma unroll
  for (int mf = 0; mf < 4; ++mf)
    #pragma unroll
    for (int rr = 0; rr < 4; ++rr) {
      float m_ = runm[mf][rr], s_ = runs[mf][rr];
      #pragma unroll
      for (int o = 1; o < 16; o <<= 1) {
        float om = __shfl_xor(m_, o);
        float os = __shfl_xor(s_, o);
        float nm = fmaxf(m_, om);
        s_ = s_ * fexp(m_ - nm) + os * fexp(om - nm);
        m_ = nm;
      }
      if (lr == 0) {
        int rowl = mf * 16 + g * 4 + rr;
        wm_s[wid][rowl] = m_;
        ws_s[wid][rowl] = s_;
      }
    }
  __syncthreads();
  if (tid < 64) {
    int bo = bl_off[tid];
    if (bo >= 0) {
      float M = fmaxf(fmaxf(wm_s[0][tid], wm_s[1][tid]), fmaxf(wm_s[2][tid], wm_s[3][tid]));
      float S = ws_s[0][tid] * fexp(wm_s[0][tid] - M) + ws_s[1][tid] * fexp(wm_s[1][tid] - M)
              + ws_s[2][tid] * fexp(wm_s[2][tid] - M) + ws_s[3][tid] * fexp(wm_s[3][tid] - M);
      float lse = M + flog(S);
      lpb[bo] = l0_s[tid] - lse;
      int eo = em_off[tid];
      if (eo >= 0) lpe[eo] = lt_s[tid] - lse;
    }
  }
}

// ---------------- Kernel 3: alpha wavefront DP + loss ----------------
__global__ __launch_bounds__(384) void alpha_kernel(
    const float* __restrict__ lpb, const float* __restrict__ lpe,
    const int* __restrict__ ilen, const int* __restrict__ ulen_,
    float* __restrict__ out) {
  __shared__ float A0[B_DIM][UP1], A1[B_DIM][UP1];
  __shared__ float afin[B_DIM];
  const int tid = threadIdx.x;
  const int b = tid / UP1;
  const int u = tid - b * UP1;
  const bool act = tid < B_DIM * UP1;
  const float NEG = -1e30f;

  int tlen = 1, ulen = 0;
  if (act) { tlen = ilen[b]; ulen = ulen_[b]; }
  if (tid < B_DIM) afin[tid] = 0.f;
  if (act) A0[b][u] = (u == 0) ? 0.f : NEG;
  __syncthreads();

  // prefetch for d = 1
  float bl = NEG, em = NEG;
  {
    int t = 1 - u;
    if (act && t >= 1 && t <= T_DIM - 1) bl = lpb[(b * T_DIM + (t - 1)) * UP1 + u];
    if (act && u >= 1 && t >= 0 && t <= T_DIM - 1) em = lpe[(b * T_DIM + t) * U_DIM + (u - 1)];
  }
  float (*Dp)[UP1] = A0;
  float (*Dc)[UP1] = A1;
  for (int d = 1; d <= T_DIM - 1 + U_DIM; ++d) {
    int t = d - u;
    float val = NEG;
    if (act) {
      bool cell = (t >= 0 && t <= T_DIM - 1);
      float a = (cell && t >= 1) ? (Dp[b][u] + bl) : NEG;
      float e = (cell && u >= 1) ? (Dp[b][u - 1] + em) : NEG;
      float mx = fmaxf(a, e), mn = fminf(a, e);
      val = mx + flog(1.0f + fexp(mn - mx));
      if (u == ulen && t == tlen - 1) afin[b] = val;
    }
    // prefetch loads for d+1
    {
      int t2 = d + 1 - u;
      bl = NEG; em = NEG;
      if (act && t2 >= 1 && t2 <= T_DIM - 1) bl = lpb[(b * T_DIM + (t2 - 1)) * UP1 + u];
      if (act && u >= 1 && t2 >= 0 && t2 <= T_DIM - 1) em = lpe[(b * T_DIM + t2) * U_DIM + (u - 1)];
    }
    if (act) Dc[b][u] = val;
    __syncthreads();
    float (*tmp)[UP1] = Dp; Dp = Dc; Dc = tmp;
  }
  if (tid == 0) {
    float s = 0.f;
    for (int bb = 0; bb < B_DIM; ++bb) {
      int tl = ilen[bb], ul = ulen_[bb];
      s += afin[bb] + lpb[(bb * T_DIM + (tl - 1)) * UP1 + ul];
    }
    out[0] = -s / (float)B_DIM;
  }
}

// ---------------- launcher ----------------
extern "C" void kernel_launch(void* const* d_in, const int* in_sizes, int n_in,
                              void* d_out, int out_size, void* d_ws, size_t ws_size,
                              hipStream_t stream) {
  const float* enc = (const float*)d_in[0];
  const float* dec = (const float*)d_in[1];
  const float* Wf  = (const float*)d_in[2];
  const float* bfv = (const float*)d_in[3];
  const float* Wp  = (const float*)d_in[4];
  const float* bp  = (const float*)d_in[5];
  const int* targets = (const int*)d_in[6];
  const int* ilen    = (const int*)d_in[7];
  const int* ulen    = (const int*)d_in[8];
  float* out = (float*)d_out;
  char* ws = (char*)d_ws;

  short* WfB = (short*)(ws + 0);          //   655360 B
  short* WpB = (short*)(ws + 655360);     //  1048576 B
  float* ep  = (float*)(ws + 1703936);    //  2457600 B
  float* dp  = (float*)(ws + 4161536);    //   663552 B
  float* lpb = (float*)(ws + 4825088);    //   388800 B
  float* lpe = (float*)(ws + 5213888);    //   384000 B -> total 5597888 B

  cvt_kernel<<<832, 256, 0, stream>>>(Wf, Wp, WfB, WpB);
  proj_kernel<<<25, 256, 0, stream>>>(enc, dec, WfB, bfv, ep, dp);
  joint_kernel<<<(NROWS + 63) / 64, 256, 65536, stream>>>(ep, dp, WpB, bp, targets, lpb, lpe);
  alpha_kernel<<<1, 384, 0, stream>>>(lpb, lpe, ilen, ulen, out);
}